// Round 7
// baseline (164.193 us; speedup 1.0000x reference)
//
#include <hip/hip_runtime.h>
#include <hip/hip_bf16.h>
#include <cstdint>
#include <cmath>

#define SQL 2048
#define SKVL 2048
#define DD 128
#define NB 16
#define QBLK 32
#define KVB 32
#define NT (SKVL / KVB)

typedef __attribute__((ext_vector_type(8))) short short8;
typedef __attribute__((ext_vector_type(4))) float f32x4;

__device__ __forceinline__ ushort f2bf(float x) {
    union { float f; uint32_t u; } v; v.f = x;
    uint32_t r = v.u + 0x7FFFu + ((v.u >> 16) & 1u);
    return (ushort)(r >> 16);
}

// fp32 -> bf16 with scale folded in; 8 elements/thread. (Used for Q.)
__global__ void convert_scale_k(const float* __restrict__ in, ushort* __restrict__ out, float scale) {
    size_t i = (size_t)blockIdx.x * blockDim.x + threadIdx.x;
    const f32x4* p = (const f32x4*)in + i * 2;
    f32x4 a = p[0], b = p[1];
    short8 o;
    o[0] = (short)f2bf(a[0] * scale);
    o[1] = (short)f2bf(a[1] * scale);
    o[2] = (short)f2bf(a[2] * scale);
    o[3] = (short)f2bf(a[3] * scale);
    o[4] = (short)f2bf(b[0] * scale);
    o[5] = (short)f2bf(b[1] * scale);
    o[6] = (short)f2bf(b[2] * scale);
    o[7] = (short)f2bf(b[3] * scale);
    *((short8*)out + i) = o;
}

// K fp32 [B][SKV][128] -> tiled swizzled bf16 [B][SKV/32][32 rows x 128 cols].
// Within an 8KB tile: elem (r,c) -> r*128 + ((c>>3)^(r&7))*8 + (c&7).
__global__ void convert_k_tiled(const float* __restrict__ in, ushort* __restrict__ out) {
    int gid = blockIdx.x * blockDim.x + threadIdx.x;   // one 16B out-chunk (8 elems)
    int c16 = gid & 15;
    int rg  = gid >> 4;            // b*SKV + kv
    int r   = rg & 31;
    int tile = rg >> 5;            // b*64 + kt
    const f32x4* p = (const f32x4*)(in + (size_t)rg * DD + c16 * 8);
    f32x4 a = p[0], b = p[1];
    short8 o;
    o[0] = (short)f2bf(a[0]); o[1] = (short)f2bf(a[1]);
    o[2] = (short)f2bf(a[2]); o[3] = (short)f2bf(a[3]);
    o[4] = (short)f2bf(b[0]); o[5] = (short)f2bf(b[1]);
    o[6] = (short)f2bf(b[2]); o[7] = (short)f2bf(b[3]);
    int cs = c16 ^ (r & 7);
    *(short8*)(out + ((size_t)tile << 12) + r * 128 + cs * 8) = o;
}

// V fp32 [B][SKV][128] -> V^T tiled bf16 [B][SKV/32][128 d-rows x 32 kv].
// kv permuted to the PV mfma slot map: logical chunk cs elem j -> kv =
// (j>>2)*16 + cs*4 + (j&3); storage chunk cs' = cs ^ ((d>>1)&3) (XOR swizzle).
__global__ void convert_vt_tiled(const float* __restrict__ v, ushort* __restrict__ vt) {
    __shared__ float tile[32][129];
    int bid = blockIdx.x;          // b*64 + kt
    int kt = bid & 63;
    int b  = bid >> 6;
    int tx = threadIdx.x;
    const float* src = v + ((size_t)b * SKVL + (size_t)kt * 32) * DD;
#pragma unroll
    for (int i = 0; i < 16; ++i) {
        int e = i * 256 + tx;      // 4096 elems
        tile[e >> 7][e & 127] = src[e];
    }
    __syncthreads();
    ushort* dst = vt + ((size_t)bid << 12);
#pragma unroll
    for (int i = 0; i < 2; ++i) {
        int q = i * 256 + tx;      // 512 chunks: d(128) x cs'(4)
        int d = q >> 2;
        int csp = q & 3;
        int cs = csp ^ ((d >> 1) & 3);
        short8 o;
#pragma unroll
        for (int j = 0; j < 8; ++j) {
            int kv = (j >> 2) * 16 + cs * 4 + (j & 3);
            o[j] = (short)f2bf(tile[kv][d]);
        }
        *(short8*)(dst + d * 32 + csp * 8) = o;
    }
}

#define GLD_LDS16(gsrc, ldst) \
    __builtin_amdgcn_global_load_lds((const __attribute__((address_space(1))) uint32_t*)(gsrc), \
                                     (__attribute__((address_space(3))) uint32_t*)(ldst), 16, 0, 0)

// Flash attention fwd. Grid = B * SQ/32 = 1024 blocks, 128 thr (2 waves)
// -> 4 independent blocks/CU (32KB LDS each) so barrier groups de-phase and
// MFMA/VALU/LDS pipes overlap across blocks. K/V^T double-buffered in LDS,
// staged via global_load_lds from the pre-swizzled workspace. Defer-max
// online softmax (shfls only on the cold path), cvt_pk P-pack, setprio.
__global__ __launch_bounds__(128, 2) void fattn(
    const ushort* __restrict__ qb, const ushort* __restrict__ kbt,
    const ushort* __restrict__ vbt, float* __restrict__ out)
{
    __shared__ short8 kls[2][512];   // [buf][r*16 + chunk] 8KB
    __shared__ short8 vls[2][512];   // [buf][d*4 + chunk]  8KB

    int bid = blockIdx.x;
    // XCD-bijective swizzle: 1024 = 8 XCDs x 128 -> 2 batches' K/V per XCD L2.
    int swz = (bid & 7) * 128 + (bid >> 3);
    int b  = swz >> 6;               // 64 q-tiles per batch
    int qt = swz & 63;
    int lane = threadIdx.x & 63;
    int w = threadIdx.x >> 6;        // 0..1
    int g = lane >> 4;
    int qi = lane & 15;
    int rx = qi & 7;
    int vx = g ^ ((qi >> 1) & 3);    // V chunk swizzle, constant per lane
    int qrow = qt * QBLK + w * 16 + qi;

    const ushort* ktile0 = kbt + ((size_t)(b * NT) << 12);
    const ushort* vtile0 = vbt + ((size_t)(b * NT) << 12);

    // Q fragments: lane holds q=qi, d-slots ks*32 + g*8 + j.
    const ushort* qptr = qb + ((size_t)b * SQL + qrow) * DD;
    short8 qf[4];
#pragma unroll
    for (int ks = 0; ks < 4; ++ks)
        qf[ks] = *(const short8*)(qptr + ks * 32 + g * 8);

    f32x4 acc[8];
#pragma unroll
    for (int i = 0; i < 8; ++i) acc[i] = (f32x4)0.f;
    float m = -1e30f, lsum = 0.f;

    // prologue: stage tile 0 (each wave stages 4KB of K and 4KB of V)
#pragma unroll
    for (int i = 0; i < 4; ++i) {
        int off = w * 4096 + i * 1024;   // wave-uniform LDS byte offset
        GLD_LDS16((const char*)ktile0 + off + lane * 16, (char*)&kls[0][0] + off);
        GLD_LDS16((const char*)vtile0 + off + lane * 16, (char*)&vls[0][0] + off);
    }
    __syncthreads();

    for (int t = 0; t < NT; ++t) {
        int cur = t & 1, nxt = cur ^ 1;
        if (t + 1 < NT) {
            const char* ks = (const char*)ktile0 + ((size_t)(t + 1) << 13);
            const char* vs = (const char*)vtile0 + ((size_t)(t + 1) << 13);
#pragma unroll
            for (int i = 0; i < 4; ++i) {
                int off = w * 4096 + i * 1024;
                GLD_LDS16(ks + off + lane * 16, (char*)&kls[nxt][0] + off);
                GLD_LDS16(vs + off + lane * 16, (char*)&vls[nxt][0] + off);
            }
        }
        // ---- QK^T from LDS: S^T = mfma(K, Q) ----
        f32x4 st[2];
        __builtin_amdgcn_s_setprio(1);
#pragma unroll
        for (int sub = 0; sub < 2; ++sub) {
            f32x4 s = (f32x4)0.f;
            int r = sub * 16 + qi;
#pragma unroll
            for (int ks = 0; ks < 4; ++ks) {
                short8 kf = kls[cur][r * 16 + ((ks * 4 + g) ^ rx)];
                s = __builtin_amdgcn_mfma_f32_16x16x32_bf16(kf, qf[ks], s, 0, 0, 0);
            }
            st[sub] = s;
        }
        __builtin_amdgcn_s_setprio(0);
        // ---- online softmax, defer-max; shfls only on the cold path ----
        float m0 = fmaxf(fmaxf(st[0][0], st[0][1]), fmaxf(st[0][2], st[0][3]));
        float m1 = fmaxf(fmaxf(st[1][0], st[1][1]), fmaxf(st[1][2], st[1][3]));
        float vmax = fmaxf(m0, m1);
        if (__any(vmax > m + 11.5f)) {
            float tmax = fmaxf(vmax, __shfl_xor(vmax, 16));
            tmax = fmaxf(tmax, __shfl_xor(tmax, 32));
            float mnew = fmaxf(m, tmax);
            float alpha = exp2f(m - mnew);
            m = mnew;
            lsum *= alpha;
#pragma unroll
            for (int i = 0; i < 8; ++i) {
                acc[i][0] *= alpha; acc[i][1] *= alpha;
                acc[i][2] *= alpha; acc[i][3] *= alpha;
            }
        }
        float pv[8];
#pragma unroll
        for (int s = 0; s < 2; ++s) {
            pv[s * 4 + 0] = exp2f(st[s][0] - m);
            pv[s * 4 + 1] = exp2f(st[s][1] - m);
            pv[s * 4 + 2] = exp2f(st[s][2] - m);
            pv[s * 4 + 3] = exp2f(st[s][3] - m);
        }
        lsum += ((pv[0] + pv[1]) + (pv[2] + pv[3])) + ((pv[4] + pv[5]) + (pv[6] + pv[7]));
        union { short8 v; uint32_t u[4]; } P;
#pragma unroll
        for (int i = 0; i < 4; ++i)
            asm("v_cvt_pk_bf16_f32 %0, %1, %2" : "=v"(P.u[i]) : "v"(pv[2 * i]), "v"(pv[2 * i + 1]));
        // ---- PV from LDS: O^T += V^T * P^T (one MFMA per d-tile) ----
        __builtin_amdgcn_s_setprio(1);
#pragma unroll
        for (int dt = 0; dt < 8; ++dt) {
            int d = dt * 16 + qi;
            acc[dt] = __builtin_amdgcn_mfma_f32_16x16x32_bf16(
                vls[cur][d * 4 + vx], P.v, acc[dt], 0, 0, 0);
        }
        __builtin_amdgcn_s_setprio(0);
        __syncthreads();   // stage(t+1) done (vmcnt0), reads of cur done
    }

    lsum += __shfl_xor(lsum, 16);
    lsum += __shfl_xor(lsum, 32);
    float inv = 1.f / lsum;
    float* optr = out + ((size_t)b * SQL + qrow) * DD + g * 4;
#pragma unroll
    for (int dt = 0; dt < 8; ++dt) {
        f32x4 o;
        o[0] = acc[dt][0] * inv; o[1] = acc[dt][1] * inv;
        o[2] = acc[dt][2] * inv; o[3] = acc[dt][3] * inv;
        *(f32x4*)(optr + dt * 16) = o;
    }
}

extern "C" void kernel_launch(void* const* d_in, const int* in_sizes, int n_in,
                              void* d_out, int out_size, void* d_ws, size_t ws_size,
                              hipStream_t stream) {
    const float* q = (const float*)d_in[0];
    const float* k = (const float*)d_in[1];
    const float* v = (const float*)d_in[2];
    float* out = (float*)d_out;

    uint8_t* w = (uint8_t*)d_ws;
    size_t tsz = (size_t)NB * SQL * DD * sizeof(ushort);  // 8 MB per tensor
    ushort* qb  = (ushort*)w;
    ushort* kbt = (ushort*)(w + tsz);
    ushort* vbt = (ushort*)(w + 2 * tsz);

    float qscale = 1.4426950408889634f / sqrtf((float)DD);
    int n8 = NB * SQL * DD / 8;
    convert_scale_k<<<n8 / 256, 256, 0, stream>>>(q, qb, qscale);
    convert_k_tiled<<<NB * SKVL * 16 / 256, 256, 0, stream>>>(k, kbt);
    convert_vt_tiled<<<NB * (SKVL / 32), 256, 0, stream>>>(v, vbt);
    fattn<<<NB * (SQL / QBLK), 128, 0, stream>>>(qb, kbt, vbt, out);
}